// Round 1
// baseline (140.782 us; speedup 1.0000x reference)
//
#include <hip/hip_runtime.h>
#include <math.h>

#define NQ   12
#define NL   4
#define BLK  256

typedef float v4f  __attribute__((ext_vector_type(4)));
typedef __fp16 v8h __attribute__((ext_vector_type(8)));

// Inverse CNOT-ring map (apply CNOTs in forward order). GF(2)-linear.
// final[i] = preC[sigma(i)]  =>  store preC[j] at slot sigma_inv(j).
__device__ __forceinline__ constexpr int sigma_inv_c(int i) {
    int j = i;
    for (int c = 0; c < NQ; ++c) {
        int t = (c + 1) % NQ;
        int cb = (j >> (NQ - 1 - c)) & 1;
        j ^= cb << (NQ - 1 - t);
    }
    return j;
}

// State buffer: amp (col CC(8b), row r(4b)) as interleaved (re,im) f16 pair.
// 16B line = 4 amps: line = CC*4 + (r>>2); hw-in-line = (r&3)*2 + part.
// Line swizzle: bits 2..0 ^= bits 5..3 ^ bits 9..7 — verified <=2-way for
// both the fragment reads (nn in C-low) and column writes (nn in C-high).
__device__ __forceinline__ constexpr int lswz(int l) {
    return l ^ (((l >> 3) ^ (l >> 7)) & 7);
}

__device__ __forceinline__ unsigned pk2(float a, float b) {
    return __builtin_bit_cast(unsigned, __builtin_amdgcn_cvt_pkrtz(a, b));
}

// ---- pre-kernel: fused gates -> 12 U16 matrices -> f16 B-fragments in d_ws ----
// K-interleaved rows: B1[2r]=Ur^T row r, B1[2r+1]=-Ui^T; B2[2r]=Ui^T, B2[2r+1]=Ur^T.
// Fragment lane order: value B[k][n] at hw ((k>>3)*16+n)*8+(k&7).
__device__ __forceinline__ int fslot(int k, int n) {
    return ((k >> 3) * 16 + n) * 8 + (k & 7);
}

// One block per matrix (12 blocks): shortens the serial pre-kernel bubble.
__global__ __launch_bounds__(BLK) void gate_kernel(
    const float* __restrict__ qw, __fp16* __restrict__ gout)
{
    __shared__ float G[NQ][8];
    const int t = threadIdx.x;
    const int mat = blockIdx.x;               // 0..11
    const int layer = mat / 3, ph = mat - 3 * layer;
    if (t < NQ) {
        const int p = layer * 3 * NQ + 3 * t;
        float t1 = qw[p], t2 = qw[p + 1], t3 = qw[p + 2];
        float a, b, c, d, gr, h;
        sincosf(0.5f * t1, &b, &a);   // RX
        sincosf(0.5f * t2, &d, &c);   // RY
        sincosf(0.5f * t3, &h, &gr);  // RZ
        float m00r =  c * a, m00i =  d * b;
        float m01r = -d * a, m01i = -c * b;
        float m10r =  d * a, m10i = -c * b;
        float m11r =  c * a, m11i = -d * b;
        float* g = G[t];
        g[0] = gr * m00r + h * m00i;  g[1] = gr * m00i - h * m00r;
        g[2] = gr * m01r + h * m01i;  g[3] = gr * m01i - h * m01r;
        g[4] = gr * m10r - h * m10i;  g[5] = gr * m10i + h * m10r;
        g[6] = gr * m11r - h * m11i;  g[7] = gr * m11i + h * m11r;
    }
    __syncthreads();
    const int n = t & 15, r = t >> 4;
    const int wbase = (ph == 0) ? 8 : (ph == 1) ? 4 : 0;
    float cr = 1.f, ci = 0.f;
    #pragma unroll
    for (int b = 0; b < 4; ++b) {         // bit (3-b) of row <-> wire wbase+b
        const float* g = G[wbase + b];
        const int rb = (r >> (3 - b)) & 1, nb = (n >> (3 - b)) & 1;
        const float er = g[(nb * 2 + rb) * 2], ei = g[(nb * 2 + rb) * 2 + 1];
        const float xr = cr * er - ci * ei, xi = cr * ei + ci * er;
        cr = xr; ci = xi;
    }
    __fp16* b1 = gout + (mat * 2 + 0) * 512;
    __fp16* b2 = gout + (mat * 2 + 1) * 512;
    b1[fslot(2 * r, n)]     = (__fp16)cr;
    b1[fslot(2 * r + 1, n)] = (__fp16)(-ci);
    b2[fslot(2 * r, n)]     = (__fp16)ci;
    b2[fslot(2 * r + 1, n)] = (__fp16)cr;
}

// A-fragment: lane (nn,g) k=8g..8g+7 -> amps r=4g..4g+3, (re,im) interleaved.
#define READ_FRAGS(SRC)                                                     \
    _Pragma("unroll")                                                       \
    for (int q = 0; q < 4; ++q)                                             \
        af[q] = __builtin_bit_cast(v8h, *(const uint4*)&sh[(SRC) +          \
                    lswz((((wv) << 6) | (q << 4) | nn) * 4 + g) * 8]);

#define MFMA_PHASE(MAT)                                                     \
    { const v8h b1 = gf[((MAT) * 2 + 0) * 64 + lane];                       \
      const v8h b2 = gf[((MAT) * 2 + 1) * 64 + lane];                       \
      _Pragma("unroll")                                                     \
      for (int q = 0; q < 4; ++q) {                                         \
          d1[q] = __builtin_amdgcn_mfma_f32_16x16x32_f16(af[q], b1, zf, 0, 0, 0); \
          d2[q] = __builtin_amdgcn_mfma_f32_16x16x32_f16(af[q], b2, zf, 0, 0, 0); \
      } }

// Element (q,rg): new row' = 4g+rg, col' = nn<<4|wv<<2|q -> one b128 per q.
#define WRITE_COLS(DST)                                                     \
    _Pragma("unroll")                                                       \
    for (int q = 0; q < 4; ++q) {                                           \
        const int CCn = (nn << 4) | (wv << 2) | q;                          \
        *(uint4*)&sh[(DST) + lswz(CCn * 4 + g) * 8] =                       \
            make_uint4(pk2(d1[q].x, d2[q].x), pk2(d1[q].y, d2[q].y),        \
                       pk2(d1[q].z, d2[q].z), pk2(d1[q].w, d2[q].w));       \
    }

// Phase-C out -> phase-A container with sigma folded in: b32 (re,im) scatter.
#define WRITE_SIGMA(DST)                                                    \
    _Pragma("unroll")                                                       \
    for (int q = 0; q < 4; ++q) {                                           \
        const int iq = ifix ^ sigma_inv_c(q << 4);                          \
        _Pragma("unroll")                                                   \
        for (int rg = 0; rg < 4; ++rg) {                                    \
            const int ii = iq ^ sigma_inv_c(rg);                            \
            *(unsigned*)&sh[(DST) + lswz(ii >> 2) * 8 + (ii & 3) * 2] =     \
                pk2(d1[q][rg], d2[q][rg]);                                  \
        }                                                                   \
    }

__global__ __launch_bounds__(BLK, 8) void qsim_kernel(
    const float* __restrict__ x,      // (B, 12)
    const __fp16* __restrict__ gates, // 12 x (B1,B2) f16 fragment tables (d_ws)
    const float* __restrict__ dw,     // (12, 12)
    const float* __restrict__ db,     // (12,)
    float* __restrict__ out)          // (B, 12)
{
    // Single in-place 16KB state buffer (was 2x16KB ping-pong):
    // every phase reads all its inputs into registers, barrier, then writes
    // back into the same buffer. 16KB/block -> 8 blocks/CU (wave-capped).
    __shared__ __align__(16) __fp16 sh[8192];
    float* xv    = (float*)sh;
    float* enc_c = (float*)sh + 16;
    float* enc_s = (float*)sh + 32;
    float* red   = (float*)sh;

    const int tid  = threadIdx.x;
    const int lane = tid & 63;
    const int wv   = tid >> 6;
    const int s    = blockIdx.x;
    const int nn = lane & 15, g = lane >> 4;
    const v8h* gf = (const v8h*)gates;
    const v4f zf = {0.f, 0.f, 0.f, 0.f};

    if (tid < NQ) xv[tid] = x[s * NQ + tid];
    __syncthreads();
    if (tid < NQ) {
        float ss = 0.f;
        #pragma unroll
        for (int j = 0; j < NQ; ++j) ss += xv[j] * xv[j];
        float inv = rsqrtf(fmaxf(ss, 1e-12f));
        float mx = 0.f;
        #pragma unroll
        for (int j = 0; j < NQ; ++j) mx = fmaxf(mx, fabsf(xv[j] * inv));
        float ang = 3.14159265358979323846f * (xv[tid] * inv) / (mx + 1e-8f);
        float cc, sn;
        sincosf(0.5f * ang, &sn, &cc);
        enc_c[tid] = cc; enc_s[tid] = sn;
    }
    __syncthreads();

    // ---- product-state init as phase-A A-fragments (interleaved re/im) ----
    v8h af[4];
    {
        #define PICK(W, B) ((B) ? enc_s[W] : enc_c[W])
        float R4[4];
        #pragma unroll
        for (int t = 0; t < 4; ++t) {
            const int r = 4 * g + t;
            R4[t] = PICK(8, (r >> 3) & 1) * PICK(9, (r >> 2) & 1)
                  * PICK(10, (r >> 1) & 1) * PICK(11, r & 1);
        }
        const float Pfix = PICK(0, (wv >> 1) & 1) * PICK(1, wv & 1)
                         * PICK(4, (nn >> 3) & 1) * PICK(5, (nn >> 2) & 1)
                         * PICK(6, (nn >> 1) & 1) * PICK(7, nn & 1);
        #pragma unroll
        for (int q = 0; q < 4; ++q) {
            const float Pq = Pfix * PICK(2, (q >> 1) & 1) * PICK(3, q & 1);
            #pragma unroll
            for (int t = 0; t < 4; ++t) {
                af[q][2 * t]     = (__fp16)(Pq * R4[t]);
                af[q][2 * t + 1] = (__fp16)0.f;
            }
        }
        #undef PICK
    }
    __syncthreads();   // enc reads done before buffer is overwritten

    const int ifix = sigma_inv_c((nn << 8) | (wv << 6) | (g << 2));

    v4f d1[4], d2[4];
    #pragma unroll 1
    for (int l = 0; l < NL; ++l) {
        if (l > 0) {
            READ_FRAGS(0)
            __syncthreads();   // all reads landed before phase-A writes
        }
        MFMA_PHASE(l * 3 + 0)             // wires 8..11
        WRITE_COLS(0)
        __syncthreads();

        READ_FRAGS(0)
        __syncthreads();                  // reads landed before phase-B writes
        MFMA_PHASE(l * 3 + 1)             // wires 4..7
        WRITE_COLS(0)
        __syncthreads();

        READ_FRAGS(0)
        __syncthreads();                  // reads landed before sigma scatter
        MFMA_PHASE(l * 3 + 2)             // wires 0..3
        if (l < NL - 1) {
            WRITE_SIGMA(0)
            __syncthreads();
        }
    }

    // ---- Z expectations via 16-pt Walsh-Hadamard over (q,rg) ----
    // vals[w] = t_w * WHT(pr)[f_w]: sigma_inv is GF(2)-linear, so the per-
    // element sign is a character of the 4-bit (q,rg) group.
    float pr[16];
    #pragma unroll
    for (int q = 0; q < 4; ++q)
        #pragma unroll
        for (int rg = 0; rg < 4; ++rg)
            pr[q * 4 + rg] = d1[q][rg] * d1[q][rg] + d2[q][rg] * d2[q][rg];
    #pragma unroll
    for (int st = 1; st < 16; st <<= 1) {
        #pragma unroll
        for (int i = 0; i < 16; ++i) {
            if (!(i & st)) {
                const float a = pr[i], b = pr[i ^ st];
                pr[i] = a + b; pr[i ^ st] = a - b;
            }
        }
    }
    float vals[NQ];
    #pragma unroll
    for (int w = 0; w < NQ; ++w) {
        const int sb = 11 - w;
        const int f = (((sigma_inv_c(0x20) >> sb) & 1) << 3)
                    | (((sigma_inv_c(0x10) >> sb) & 1) << 2)
                    | (((sigma_inv_c(2)    >> sb) & 1) << 1)
                    |  ((sigma_inv_c(1)    >> sb) & 1);
        const float v = pr[f];
        vals[w] = ((ifix >> sb) & 1) ? -v : v;
    }
    #pragma unroll
    for (int m = 1; m <= 32; m <<= 1) {
        #pragma unroll
        for (int w = 0; w < NQ; ++w) vals[w] += __shfl_xor(vals[w], m);
    }
    __syncthreads();   // all waves done with sh before red alias is written
    if (lane == 0) {
        #pragma unroll
        for (int w = 0; w < NQ; ++w) red[wv * NQ + w] = vals[w];
    }
    __syncthreads();
    if (tid < NQ)
        red[48 + tid] = red[tid] + red[NQ + tid] + red[2 * NQ + tid] + red[3 * NQ + tid];
    __syncthreads();
    if (tid < NQ) {
        float v = db[tid];
        #pragma unroll
        for (int w = 0; w < NQ; ++w) v += red[48 + w] * dw[w * NQ + tid];
        out[s * NQ + tid] = tanhf(v);
    }
}

extern "C" void kernel_launch(void* const* d_in, const int* in_sizes, int n_in,
                              void* d_out, int out_size, void* d_ws, size_t ws_size,
                              hipStream_t stream) {
    const float* x  = (const float*)d_in[0];
    const float* qw = (const float*)d_in[1];
    const float* dw = (const float*)d_in[2];
    const float* db = (const float*)d_in[3];
    float* out = (float*)d_out;
    __fp16* gates = (__fp16*)d_ws;          // 12 x 2 x 512 f16 = 24576 B
    int batch = in_sizes[0] / NQ;
    gate_kernel<<<12, BLK, 0, stream>>>(qw, gates);
    qsim_kernel<<<batch, BLK, 0, stream>>>(x, gates, dw, db, out);
}

// Round 2
// 138.353 us; speedup vs baseline: 1.0176x; 1.0176x over previous
//
#include <hip/hip_runtime.h>
#include <math.h>

#define NQ   12
#define NL   4
#define BLK  256

typedef float v4f  __attribute__((ext_vector_type(4)));
typedef __fp16 v8h __attribute__((ext_vector_type(8)));
typedef unsigned v4u __attribute__((ext_vector_type(4)));

// Inverse CNOT-ring map (apply CNOTs in forward order). GF(2)-linear.
// final[i] = preC[sigma(i)]  =>  store preC[j] at slot sigma_inv(j).
__device__ __forceinline__ constexpr int sigma_inv_c(int i) {
    int j = i;
    for (int c = 0; c < NQ; ++c) {
        int t = (c + 1) % NQ;
        int cb = (j >> (NQ - 1 - c)) & 1;
        j ^= cb << (NQ - 1 - t);
    }
    return j;
}

// State buffer: amp (col CC(8b), row r(4b)) as interleaved (re,im) f16 pair.
// 16B line = 4 amps: line = CC*4 + (r>>2); hw-in-line = (r&3)*2 + part.
// Line swizzle: bits 2..0 ^= bits 5..3 ^ bits 9..7 — verified <=2-way for
// both the fragment reads (nn in C-low) and column writes (nn in C-high).
__device__ __forceinline__ constexpr int lswz(int l) {
    return l ^ (((l >> 3) ^ (l >> 7)) & 7);
}

__device__ __forceinline__ unsigned pk2(float a, float b) {
    return __builtin_bit_cast(unsigned, __builtin_amdgcn_cvt_pkrtz(a, b));
}

// B2 fragment derived in-register from B1.
// B1 32-bit word w = (lo: Re(U^T), hi: -Im(U^T)); B2 word = (lo: Im, hi: Re).
// rotate16(w) = (lo: -Im, hi: Re); XOR 0x8000 flips the sign of the low f16.
__device__ __forceinline__ v8h derive_b2(v8h b1) {
    v4u w = __builtin_bit_cast(v4u, b1);
    v4u r;
    #pragma unroll
    for (int i = 0; i < 4; ++i) {
        const unsigned rot = (w[i] >> 16) | (w[i] << 16);
        r[i] = rot ^ 0x8000u;
    }
    return __builtin_bit_cast(v8h, r);
}

// ---- pre-kernel: fused gates -> 12 U16 matrices -> f16 B-fragments in d_ws ----
// K-interleaved rows: B1[2r]=Ur^T row r, B1[2r+1]=-Ui^T; B2[2r]=Ui^T, B2[2r+1]=Ur^T.
// Fragment lane order: value B[k][n] at hw ((k>>3)*16+n)*8+(k&7).
__device__ __forceinline__ int fslot(int k, int n) {
    return ((k >> 3) * 16 + n) * 8 + (k & 7);
}

// One block per matrix (12 blocks): shortens the serial pre-kernel bubble.
__global__ __launch_bounds__(BLK) void gate_kernel(
    const float* __restrict__ qw, __fp16* __restrict__ gout)
{
    __shared__ float G[NQ][8];
    const int t = threadIdx.x;
    const int mat = blockIdx.x;               // 0..11
    const int layer = mat / 3, ph = mat - 3 * layer;
    if (t < NQ) {
        const int p = layer * 3 * NQ + 3 * t;
        float t1 = qw[p], t2 = qw[p + 1], t3 = qw[p + 2];
        float a, b, c, d, gr, h;
        sincosf(0.5f * t1, &b, &a);   // RX
        sincosf(0.5f * t2, &d, &c);   // RY
        sincosf(0.5f * t3, &h, &gr);  // RZ
        float m00r =  c * a, m00i =  d * b;
        float m01r = -d * a, m01i = -c * b;
        float m10r =  d * a, m10i = -c * b;
        float m11r =  c * a, m11i = -d * b;
        float* g = G[t];
        g[0] = gr * m00r + h * m00i;  g[1] = gr * m00i - h * m00r;
        g[2] = gr * m01r + h * m01i;  g[3] = gr * m01i - h * m01r;
        g[4] = gr * m10r - h * m10i;  g[5] = gr * m10i + h * m10r;
        g[6] = gr * m11r - h * m11i;  g[7] = gr * m11i + h * m11r;
    }
    __syncthreads();
    const int n = t & 15, r = t >> 4;
    const int wbase = (ph == 0) ? 8 : (ph == 1) ? 4 : 0;
    float cr = 1.f, ci = 0.f;
    #pragma unroll
    for (int b = 0; b < 4; ++b) {         // bit (3-b) of row <-> wire wbase+b
        const float* g = G[wbase + b];
        const int rb = (r >> (3 - b)) & 1, nb = (n >> (3 - b)) & 1;
        const float er = g[(nb * 2 + rb) * 2], ei = g[(nb * 2 + rb) * 2 + 1];
        const float xr = cr * er - ci * ei, xi = cr * ei + ci * er;
        cr = xr; ci = xi;
    }
    __fp16* b1 = gout + (mat * 2 + 0) * 512;
    __fp16* b2 = gout + (mat * 2 + 1) * 512;
    b1[fslot(2 * r, n)]     = (__fp16)cr;
    b1[fslot(2 * r + 1, n)] = (__fp16)(-ci);
    b2[fslot(2 * r, n)]     = (__fp16)ci;   // kept for layout compat (unread)
    b2[fslot(2 * r + 1, n)] = (__fp16)cr;
}

// A-fragment: lane (nn,g) k=8g..8g+7 -> amps r=4g..4g+3, (re,im) interleaved.
#define READ_FRAGS(SRC)                                                     \
    _Pragma("unroll")                                                       \
    for (int q = 0; q < 4; ++q)                                             \
        af[q] = __builtin_bit_cast(v8h, *(const uint4*)&sh[(SRC) +          \
                    lswz((((wv) << 6) | (q << 4) | nn) * 4 + g) * 8]);

// Fused per-q MFMA -> pack -> b128 write: accumulator live range = 8 regs,
// not 32.  Element (q,rg): row' = 4g+rg, col' = nn<<4|wv<<2|q.
#define MW_COLS(MAT, DST)                                                   \
    { const v8h b1 = gf[((MAT) * 2 + 0) * 64 + lane];                       \
      const v8h b2 = derive_b2(b1);                                         \
      _Pragma("unroll")                                                     \
      for (int q = 0; q < 4; ++q) {                                         \
          const v4f e1 = __builtin_amdgcn_mfma_f32_16x16x32_f16(af[q], b1, zf, 0, 0, 0); \
          const v4f e2 = __builtin_amdgcn_mfma_f32_16x16x32_f16(af[q], b2, zf, 0, 0, 0); \
          const int CCn = (nn << 4) | (wv << 2) | q;                        \
          *(uint4*)&sh[(DST) + lswz(CCn * 4 + g) * 8] =                     \
              make_uint4(pk2(e1.x, e2.x), pk2(e1.y, e2.y),                  \
                         pk2(e1.z, e2.z), pk2(e1.w, e2.w));                 \
      } }

// Fused per-q MFMA -> sigma scatter (b32 (re,im) pairs).
#define MW_SIGMA(MAT, DST)                                                  \
    { const v8h b1 = gf[((MAT) * 2 + 0) * 64 + lane];                       \
      const v8h b2 = derive_b2(b1);                                         \
      _Pragma("unroll")                                                     \
      for (int q = 0; q < 4; ++q) {                                         \
          const v4f e1 = __builtin_amdgcn_mfma_f32_16x16x32_f16(af[q], b1, zf, 0, 0, 0); \
          const v4f e2 = __builtin_amdgcn_mfma_f32_16x16x32_f16(af[q], b2, zf, 0, 0, 0); \
          const int iq = ifix ^ sigma_inv_c(q << 4);                        \
          _Pragma("unroll")                                                 \
          for (int rg = 0; rg < 4; ++rg) {                                  \
              const int ii = iq ^ sigma_inv_c(rg);                          \
              *(unsigned*)&sh[(DST) + lswz(ii >> 2) * 8 + (ii & 3) * 2] =   \
                  pk2(e1[rg], e2[rg]);                                      \
          } } }

// Final phase keeps the full f32 accumulator for the WHT epilogue.
#define MFMA_PHASE(MAT)                                                     \
    { const v8h b1 = gf[((MAT) * 2 + 0) * 64 + lane];                       \
      const v8h b2 = derive_b2(b1);                                         \
      _Pragma("unroll")                                                     \
      for (int q = 0; q < 4; ++q) {                                         \
          d1[q] = __builtin_amdgcn_mfma_f32_16x16x32_f16(af[q], b1, zf, 0, 0, 0); \
          d2[q] = __builtin_amdgcn_mfma_f32_16x16x32_f16(af[q], b2, zf, 0, 0, 0); \
      } }

__global__ __launch_bounds__(BLK) void qsim_kernel(
    const float* __restrict__ x,      // (B, 12)
    const __fp16* __restrict__ gates, // 12 x (B1,B2) f16 fragment tables (d_ws)
    const float* __restrict__ dw,     // (12, 12)
    const float* __restrict__ db,     // (12,)
    float* __restrict__ out)          // (B, 12)
{
    __shared__ __align__(16) __fp16 sh[16384];   // two 16KB ping-pong buffers
    float* xv    = (float*)sh;
    float* enc_c = (float*)sh + 16;
    float* enc_s = (float*)sh + 32;
    float* red   = (float*)sh;

    const int tid  = threadIdx.x;
    const int lane = tid & 63;
    const int wv   = tid >> 6;
    const int s    = blockIdx.x;
    const int nn = lane & 15, g = lane >> 4;
    const v8h* gf = (const v8h*)gates;
    const v4f zf = {0.f, 0.f, 0.f, 0.f};

    if (tid < NQ) xv[tid] = x[s * NQ + tid];
    __syncthreads();
    if (tid < NQ) {
        float ss = 0.f;
        #pragma unroll
        for (int j = 0; j < NQ; ++j) ss += xv[j] * xv[j];
        float inv = rsqrtf(fmaxf(ss, 1e-12f));
        float mx = 0.f;
        #pragma unroll
        for (int j = 0; j < NQ; ++j) mx = fmaxf(mx, fabsf(xv[j] * inv));
        float ang = 3.14159265358979323846f * (xv[tid] * inv) / (mx + 1e-8f);
        float cc, sn;
        sincosf(0.5f * ang, &sn, &cc);
        enc_c[tid] = cc; enc_s[tid] = sn;
    }
    __syncthreads();

    // ---- product-state init as phase-A A-fragments (interleaved re/im) ----
    v8h af[4];
    {
        #define PICK(W, B) ((B) ? enc_s[W] : enc_c[W])
        float R4[4];
        #pragma unroll
        for (int t = 0; t < 4; ++t) {
            const int r = 4 * g + t;
            R4[t] = PICK(8, (r >> 3) & 1) * PICK(9, (r >> 2) & 1)
                  * PICK(10, (r >> 1) & 1) * PICK(11, r & 1);
        }
        const float Pfix = PICK(0, (wv >> 1) & 1) * PICK(1, wv & 1)
                         * PICK(4, (nn >> 3) & 1) * PICK(5, (nn >> 2) & 1)
                         * PICK(6, (nn >> 1) & 1) * PICK(7, nn & 1);
        #pragma unroll
        for (int q = 0; q < 4; ++q) {
            const float Pq = Pfix * PICK(2, (q >> 1) & 1) * PICK(3, q & 1);
            #pragma unroll
            for (int t = 0; t < 4; ++t) {
                af[q][2 * t]     = (__fp16)(Pq * R4[t]);
                af[q][2 * t + 1] = (__fp16)0.f;
            }
        }
        #undef PICK
    }
    __syncthreads();   // enc reads done before buffer 0 is overwritten

    const int ifix = sigma_inv_c((nn << 8) | (wv << 6) | (g << 2));

    v4f d1[4], d2[4];
    #pragma unroll 1
    for (int l = 0; l < NL; ++l) {
        const int XA = (l & 1) * 8192;
        const int XB = 8192 - XA;

        if (l > 0) { READ_FRAGS(XB) }
        MW_COLS(l * 3 + 0, XA)            // wires 8..11
        __syncthreads();

        READ_FRAGS(XA)
        MW_COLS(l * 3 + 1, XB)            // wires 4..7
        __syncthreads();

        READ_FRAGS(XB)
        if (l < NL - 1) {
            MW_SIGMA(l * 3 + 2, XA)       // wires 0..3 + CNOT ring fold
            __syncthreads();
        } else {
            MFMA_PHASE(l * 3 + 2)         // final: keep f32 accs for WHT
        }
    }

    // ---- Z expectations via 16-pt Walsh-Hadamard over (q,rg) ----
    // vals[w] = t_w * WHT(pr)[f_w]: sigma_inv is GF(2)-linear, so the per-
    // element sign is a character of the 4-bit (q,rg) group.
    float pr[16];
    #pragma unroll
    for (int q = 0; q < 4; ++q)
        #pragma unroll
        for (int rg = 0; rg < 4; ++rg)
            pr[q * 4 + rg] = d1[q][rg] * d1[q][rg] + d2[q][rg] * d2[q][rg];
    #pragma unroll
    for (int st = 1; st < 16; st <<= 1) {
        #pragma unroll
        for (int i = 0; i < 16; ++i) {
            if (!(i & st)) {
                const float a = pr[i], b = pr[i ^ st];
                pr[i] = a + b; pr[i ^ st] = a - b;
            }
        }
    }
    float vals[NQ];
    #pragma unroll
    for (int w = 0; w < NQ; ++w) {
        const int sb = 11 - w;
        const int f = (((sigma_inv_c(0x20) >> sb) & 1) << 3)
                    | (((sigma_inv_c(0x10) >> sb) & 1) << 2)
                    | (((sigma_inv_c(2)    >> sb) & 1) << 1)
                    |  ((sigma_inv_c(1)    >> sb) & 1);
        const float v = pr[f];
        vals[w] = ((ifix >> sb) & 1) ? -v : v;
    }
    #pragma unroll
    for (int m = 1; m <= 32; m <<= 1) {
        #pragma unroll
        for (int w = 0; w < NQ; ++w) vals[w] += __shfl_xor(vals[w], m);
    }
    __syncthreads();   // all waves done with sh before red alias is written
    if (lane == 0) {
        #pragma unroll
        for (int w = 0; w < NQ; ++w) red[wv * NQ + w] = vals[w];
    }
    __syncthreads();
    if (tid < NQ)
        red[48 + tid] = red[tid] + red[NQ + tid] + red[2 * NQ + tid] + red[3 * NQ + tid];
    __syncthreads();
    if (tid < NQ) {
        float v = db[tid];
        #pragma unroll
        for (int w = 0; w < NQ; ++w) v += red[48 + w] * dw[w * NQ + tid];
        out[s * NQ + tid] = tanhf(v);
    }
}

extern "C" void kernel_launch(void* const* d_in, const int* in_sizes, int n_in,
                              void* d_out, int out_size, void* d_ws, size_t ws_size,
                              hipStream_t stream) {
    const float* x  = (const float*)d_in[0];
    const float* qw = (const float*)d_in[1];
    const float* dw = (const float*)d_in[2];
    const float* db = (const float*)d_in[3];
    float* out = (float*)d_out;
    __fp16* gates = (__fp16*)d_ws;          // 12 x 2 x 512 f16 = 24576 B
    int batch = in_sizes[0] / NQ;
    gate_kernel<<<12, BLK, 0, stream>>>(qw, gates);
    qsim_kernel<<<batch, BLK, 0, stream>>>(x, gates, dw, db, out);
}

// Round 3
// 114.739 us; speedup vs baseline: 1.2270x; 1.2058x over previous
//
#include <hip/hip_runtime.h>
#include <math.h>

#define NQ   12
#define NL   4
#define BLK  256
#define S1OFF 8192   // sample-1 state offset in __fp16 units (16 KB)

typedef float v4f  __attribute__((ext_vector_type(4)));
typedef __fp16 v8h __attribute__((ext_vector_type(8)));

// Inverse CNOT-ring map (apply CNOTs in forward order). GF(2)-linear.
// final[i] = preC[sigma(i)]  =>  store preC[j] at slot sigma_inv(j).
__device__ __forceinline__ constexpr int sigma_inv_c(int i) {
    int j = i;
    for (int c = 0; c < NQ; ++c) {
        int t = (c + 1) % NQ;
        int cb = (j >> (NQ - 1 - c)) & 1;
        j ^= cb << (NQ - 1 - t);
    }
    return j;
}

// State buffer: amp (col CC(8b), row r(4b)) as interleaved (re,im) f16 pair.
// 16B line = 4 amps: line = CC*4 + (r>>2); hw-in-line = (r&3)*2 + part.
// Line swizzle: bits 2..0 ^= bits 5..3 ^ bits 9..7 — verified <=2-way for
// both the fragment reads (nn in C-low) and column writes (nn in C-high).
__device__ __forceinline__ constexpr int lswz(int l) {
    return l ^ (((l >> 3) ^ (l >> 7)) & 7);
}

__device__ __forceinline__ unsigned pk2(float a, float b) {
    return __builtin_bit_cast(unsigned, __builtin_amdgcn_cvt_pkrtz(a, b));
}

// ---- pre-kernel: fused gates -> 12 U16 matrices -> f16 B-fragments in d_ws ----
// K-interleaved rows: B1[2r]=Ur^T row r, B1[2r+1]=-Ui^T; B2[2r]=Ui^T, B2[2r+1]=Ur^T.
// Fragment lane order: value B[k][n] at hw ((k>>3)*16+n)*8+(k&7).
__device__ __forceinline__ int fslot(int k, int n) {
    return ((k >> 3) * 16 + n) * 8 + (k & 7);
}

// One block per matrix (12 blocks): shortens the serial pre-kernel bubble.
__global__ __launch_bounds__(BLK) void gate_kernel(
    const float* __restrict__ qw, __fp16* __restrict__ gout)
{
    __shared__ float G[NQ][8];
    const int t = threadIdx.x;
    const int mat = blockIdx.x;               // 0..11
    const int layer = mat / 3, ph = mat - 3 * layer;
    if (t < NQ) {
        const int p = layer * 3 * NQ + 3 * t;
        float t1 = qw[p], t2 = qw[p + 1], t3 = qw[p + 2];
        float a, b, c, d, gr, h;
        sincosf(0.5f * t1, &b, &a);   // RX
        sincosf(0.5f * t2, &d, &c);   // RY
        sincosf(0.5f * t3, &h, &gr);  // RZ
        float m00r =  c * a, m00i =  d * b;
        float m01r = -d * a, m01i = -c * b;
        float m10r =  d * a, m10i = -c * b;
        float m11r =  c * a, m11i = -d * b;
        float* g = G[t];
        g[0] = gr * m00r + h * m00i;  g[1] = gr * m00i - h * m00r;
        g[2] = gr * m01r + h * m01i;  g[3] = gr * m01i - h * m01r;
        g[4] = gr * m10r - h * m10i;  g[5] = gr * m10i + h * m10r;
        g[6] = gr * m11r - h * m11i;  g[7] = gr * m11i + h * m11r;
    }
    __syncthreads();
    const int n = t & 15, r = t >> 4;
    const int wbase = (ph == 0) ? 8 : (ph == 1) ? 4 : 0;
    float cr = 1.f, ci = 0.f;
    #pragma unroll
    for (int b = 0; b < 4; ++b) {         // bit (3-b) of row <-> wire wbase+b
        const float* g = G[wbase + b];
        const int rb = (r >> (3 - b)) & 1, nb = (n >> (3 - b)) & 1;
        const float er = g[(nb * 2 + rb) * 2], ei = g[(nb * 2 + rb) * 2 + 1];
        const float xr = cr * er - ci * ei, xi = cr * ei + ci * er;
        cr = xr; ci = xi;
    }
    __fp16* b1 = gout + (mat * 2 + 0) * 512;
    __fp16* b2 = gout + (mat * 2 + 1) * 512;
    b1[fslot(2 * r, n)]     = (__fp16)cr;
    b1[fslot(2 * r + 1, n)] = (__fp16)(-ci);
    b2[fslot(2 * r, n)]     = (__fp16)ci;
    b2[fslot(2 * r + 1, n)] = (__fp16)cr;
}

// A-fragment: lane (nn,g) k=8g..8g+7 -> amps r=4g..4g+3, (re,im) interleaved.
#define READ_FRAGS(AF, SRC)                                                 \
    _Pragma("unroll")                                                       \
    for (int q = 0; q < 4; ++q)                                             \
        AF[q] = __builtin_bit_cast(v8h, *(const uint4*)&sh[(SRC) +          \
                    lswz((((wv) << 6) | (q << 4) | nn) * 4 + g) * 8]);

// Shared B-fragments for both samples of the phase.
#define BLOAD(MAT)                                                          \
    const v8h b1 = gf[((MAT) * 2 + 0) * 64 + lane];                         \
    const v8h b2 = gf[((MAT) * 2 + 1) * 64 + lane];

#define MFMA_ONE(AF)                                                        \
    _Pragma("unroll")                                                       \
    for (int q = 0; q < 4; ++q) {                                           \
        d1[q] = __builtin_amdgcn_mfma_f32_16x16x32_f16(AF[q], b1, zf, 0, 0, 0); \
        d2[q] = __builtin_amdgcn_mfma_f32_16x16x32_f16(AF[q], b2, zf, 0, 0, 0); \
    }

// Keep the two samples' compute regions from being cross-pipelined
// (R2 lesson: interleaving doubles live accumulators -> VGPR cliff).
#define SCHB __builtin_amdgcn_sched_barrier(0);

// Element (q,rg): new row' = 4g+rg, col' = nn<<4|wv<<2|q -> one b128 per q.
#define WRITE_COLS(DST)                                                     \
    _Pragma("unroll")                                                       \
    for (int q = 0; q < 4; ++q) {                                           \
        const int CCn = (nn << 4) | (wv << 2) | q;                          \
        *(uint4*)&sh[(DST) + lswz(CCn * 4 + g) * 8] =                       \
            make_uint4(pk2(d1[q].x, d2[q].x), pk2(d1[q].y, d2[q].y),        \
                       pk2(d1[q].z, d2[q].z), pk2(d1[q].w, d2[q].w));       \
    }

// Phase-C out -> phase-A container with sigma folded in: b32 (re,im) scatter.
#define WRITE_SIGMA(DST)                                                    \
    _Pragma("unroll")                                                       \
    for (int q = 0; q < 4; ++q) {                                           \
        const int iq = ifix ^ sigma_inv_c(q << 4);                          \
        _Pragma("unroll")                                                   \
        for (int rg = 0; rg < 4; ++rg) {                                    \
            const int ii = iq ^ sigma_inv_c(rg);                            \
            *(unsigned*)&sh[(DST) + lswz(ii >> 2) * 8 + (ii & 3) * 2] =     \
                pk2(d1[q][rg], d2[q][rg]);                                  \
        }                                                                   \
    }

// Z expectations via 16-pt Walsh-Hadamard over (q,rg) from d1/d2.
#define WHT_VALS(VALS)                                                      \
    { float pr[16];                                                         \
      _Pragma("unroll")                                                     \
      for (int q = 0; q < 4; ++q)                                           \
          _Pragma("unroll")                                                 \
          for (int rg = 0; rg < 4; ++rg)                                    \
              pr[q * 4 + rg] = d1[q][rg] * d1[q][rg] + d2[q][rg] * d2[q][rg]; \
      _Pragma("unroll")                                                     \
      for (int st = 1; st < 16; st <<= 1) {                                 \
          _Pragma("unroll")                                                 \
          for (int i = 0; i < 16; ++i) {                                    \
              if (!(i & st)) {                                              \
                  const float a = pr[i], b = pr[i ^ st];                    \
                  pr[i] = a + b; pr[i ^ st] = a - b;                        \
              }                                                             \
          }                                                                 \
      }                                                                     \
      _Pragma("unroll")                                                     \
      for (int w = 0; w < NQ; ++w) {                                        \
          const int sb = 11 - w;                                            \
          const int f = (((sigma_inv_c(0x20) >> sb) & 1) << 3)              \
                      | (((sigma_inv_c(0x10) >> sb) & 1) << 2)              \
                      | (((sigma_inv_c(2)    >> sb) & 1) << 1)              \
                      |  ((sigma_inv_c(1)    >> sb) & 1);                   \
          const float v = pr[f];                                            \
          VALS[w] = ((ifix >> sb) & 1) ? -v : v;                            \
      } }

__global__ __launch_bounds__(BLK) void qsim_kernel(
    const float* __restrict__ x,      // (B, 12)
    const __fp16* __restrict__ gates, // 12 x (B1,B2) f16 fragment tables (d_ws)
    const float* __restrict__ dw,     // (12, 12)
    const float* __restrict__ db,     // (12,)
    float* __restrict__ out,          // (B, 12)
    int batch)
{
    // Two samples per block, each with a 16 KB in-place state buffer.
    // Gates are sample-independent, so B-fragments are shared per phase.
    __shared__ __align__(16) __fp16 sh[16384];
    float* xv    = (float*)sh;        // [0..23]
    float* enc_c = (float*)sh + 32;   // [32..55]
    float* enc_s = (float*)sh + 64;   // [64..87]
    float* red   = (float*)sh;

    const int tid  = threadIdx.x;
    const int lane = tid & 63;
    const int wv   = tid >> 6;
    const int s0   = 2 * blockIdx.x;
    int s1 = s0 + 1; if (s1 >= batch) s1 = batch - 1;   // odd-batch clamp
    const int nn = lane & 15, g = lane >> 4;
    const v8h* gf = (const v8h*)gates;
    const v4f zf = {0.f, 0.f, 0.f, 0.f};

    if (tid < 2 * NQ) {
        const int smp = tid / NQ, j = tid - smp * NQ;
        xv[tid] = x[(smp ? s1 : s0) * NQ + j];
    }
    __syncthreads();
    if (tid < 2 * NQ) {
        const int base = (tid / NQ) * NQ;
        float ss = 0.f;
        #pragma unroll
        for (int j = 0; j < NQ; ++j) ss += xv[base + j] * xv[base + j];
        float inv = rsqrtf(fmaxf(ss, 1e-12f));
        float mx = 0.f;
        #pragma unroll
        for (int j = 0; j < NQ; ++j) mx = fmaxf(mx, fabsf(xv[base + j] * inv));
        float ang = 3.14159265358979323846f * (xv[tid] * inv) / (mx + 1e-8f);
        float cc, sn;
        sincosf(0.5f * ang, &sn, &cc);
        enc_c[tid] = cc; enc_s[tid] = sn;
    }
    __syncthreads();

    // ---- product-state init as phase-A A-fragments (interleaved re/im) ----
    v8h af0[4], af1[4];
    #define PICK(SMP, W, B) ((B) ? enc_s[(SMP) * NQ + (W)] : enc_c[(SMP) * NQ + (W)])
    #define INIT_AF(AF, SMP)                                                \
    {   float R4[4];                                                        \
        _Pragma("unroll")                                                   \
        for (int t = 0; t < 4; ++t) {                                       \
            const int r = 4 * g + t;                                        \
            R4[t] = PICK(SMP, 8, (r >> 3) & 1) * PICK(SMP, 9, (r >> 2) & 1) \
                  * PICK(SMP, 10, (r >> 1) & 1) * PICK(SMP, 11, r & 1);     \
        }                                                                   \
        const float Pfix = PICK(SMP, 0, (wv >> 1) & 1) * PICK(SMP, 1, wv & 1) \
                         * PICK(SMP, 4, (nn >> 3) & 1) * PICK(SMP, 5, (nn >> 2) & 1) \
                         * PICK(SMP, 6, (nn >> 1) & 1) * PICK(SMP, 7, nn & 1); \
        _Pragma("unroll")                                                   \
        for (int q = 0; q < 4; ++q) {                                       \
            const float Pq = Pfix * PICK(SMP, 2, (q >> 1) & 1) * PICK(SMP, 3, q & 1); \
            _Pragma("unroll")                                               \
            for (int t = 0; t < 4; ++t) {                                   \
                AF[q][2 * t]     = (__fp16)(Pq * R4[t]);                    \
                AF[q][2 * t + 1] = (__fp16)0.f;                             \
            }                                                               \
        }                                                                   \
    }
    INIT_AF(af0, 0)
    INIT_AF(af1, 1)
    #undef PICK
    __syncthreads();   // enc reads done before state buffers are written

    const int ifix = sigma_inv_c((nn << 8) | (wv << 6) | (g << 2));

    v4f d1[4], d2[4];
    float vals0[NQ], vals1[NQ];
    #pragma unroll 1
    for (int l = 0; l < NL; ++l) {
        if (l > 0) {
            READ_FRAGS(af0, 0)
            READ_FRAGS(af1, S1OFF)
            __syncthreads();              // all reads landed before writes
        }
        { BLOAD(l * 3 + 0)                // wires 8..11
          MFMA_ONE(af0) WRITE_COLS(0)
          SCHB
          MFMA_ONE(af1) WRITE_COLS(S1OFF) }
        __syncthreads();

        READ_FRAGS(af0, 0)
        READ_FRAGS(af1, S1OFF)
        __syncthreads();
        { BLOAD(l * 3 + 1)                // wires 4..7
          MFMA_ONE(af0) WRITE_COLS(0)
          SCHB
          MFMA_ONE(af1) WRITE_COLS(S1OFF) }
        __syncthreads();

        READ_FRAGS(af0, 0)
        READ_FRAGS(af1, S1OFF)
        if (l < NL - 1) {
            __syncthreads();
            { BLOAD(l * 3 + 2)            // wires 0..3 + CNOT ring fold
              MFMA_ONE(af0) WRITE_SIGMA(0)
              SCHB
              MFMA_ONE(af1) WRITE_SIGMA(S1OFF) }
            __syncthreads();
        } else {
            { BLOAD(l * 3 + 2)            // final: straight to WHT epilogue
              MFMA_ONE(af0)
              WHT_VALS(vals0)
              SCHB
              MFMA_ONE(af1)
              WHT_VALS(vals1) }
        }
    }

    #pragma unroll
    for (int m = 1; m <= 32; m <<= 1) {
        #pragma unroll
        for (int w = 0; w < NQ; ++w) {
            vals0[w] += __shfl_xor(vals0[w], m);
            vals1[w] += __shfl_xor(vals1[w], m);
        }
    }
    __syncthreads();   // all waves done with sh before red alias is written
    if (lane == 0) {
        #pragma unroll
        for (int w = 0; w < NQ; ++w) {
            red[wv * NQ + w]      = vals0[w];
            red[48 + wv * NQ + w] = vals1[w];
        }
    }
    __syncthreads();
    if (tid < 2 * NQ) {
        const int smp = tid / NQ, w = tid - smp * NQ;
        const float* rs = red + smp * 48;
        red[96 + tid] = rs[w] + rs[NQ + w] + rs[2 * NQ + w] + rs[3 * NQ + w];
    }
    __syncthreads();
    if (tid < 2 * NQ) {
        const int smp = tid / NQ, o = tid - smp * NQ;
        const float* rv = red + 96 + smp * NQ;
        float v = db[o];
        #pragma unroll
        for (int w = 0; w < NQ; ++w) v += rv[w] * dw[w * NQ + o];
        out[(smp ? s1 : s0) * NQ + o] = tanhf(v);
    }
}

extern "C" void kernel_launch(void* const* d_in, const int* in_sizes, int n_in,
                              void* d_out, int out_size, void* d_ws, size_t ws_size,
                              hipStream_t stream) {
    const float* x  = (const float*)d_in[0];
    const float* qw = (const float*)d_in[1];
    const float* dw = (const float*)d_in[2];
    const float* db = (const float*)d_in[3];
    float* out = (float*)d_out;
    __fp16* gates = (__fp16*)d_ws;          // 12 x 2 x 512 f16 = 24576 B
    int batch = in_sizes[0] / NQ;
    int nblk = (batch + 1) / 2;
    gate_kernel<<<12, BLK, 0, stream>>>(qw, gates);
    qsim_kernel<<<nblk, BLK, 0, stream>>>(x, gates, dw, db, out, batch);
}

// Round 4
// 113.972 us; speedup vs baseline: 1.2352x; 1.0067x over previous
//
#include <hip/hip_runtime.h>
#include <math.h>

#define NQ   12
#define NL   4
#define BLK  256
#define S1OFF 8192   // sample-1 state offset in __fp16 units (16 KB)

typedef float v4f  __attribute__((ext_vector_type(4)));
typedef __fp16 v8h __attribute__((ext_vector_type(8)));

// Inverse CNOT-ring map (apply CNOTs in forward order). GF(2)-linear.
// final[i] = preC[sigma(i)]  =>  store preC[j] at slot sigma_inv(j).
__device__ __forceinline__ constexpr int sigma_inv_c(int i) {
    int j = i;
    for (int c = 0; c < NQ; ++c) {
        int t = (c + 1) % NQ;
        int cb = (j >> (NQ - 1 - c)) & 1;
        j ^= cb << (NQ - 1 - t);
    }
    return j;
}

// State buffer: amp (col CC(8b), row r(4b)) as interleaved (re,im) f16 pair.
// 16B line = 4 amps: line = CC*4 + (r>>2); hw-in-line = (r&3)*2 + part.
// Line swizzle: bits 2..0 ^= bits 5..3 ^ bits 9..7 — verified <=2-way for
// both the fragment reads (nn in C-low) and column writes (nn in C-high).
__device__ __forceinline__ constexpr int lswz(int l) {
    return l ^ (((l >> 3) ^ (l >> 7)) & 7);
}

__device__ __forceinline__ unsigned pk2(float a, float b) {
    return __builtin_bit_cast(unsigned, __builtin_amdgcn_cvt_pkrtz(a, b));
}

// ---- pre-kernel: fused gates -> 12 U16 matrices -> f16 B-fragments in d_ws ----
// K-interleaved rows: B1[2r]=Ur^T row r, B1[2r+1]=-Ui^T; B2[2r]=Ui^T, B2[2r+1]=Ur^T.
// Fragment lane order: value B[k][n] at hw ((k>>3)*16+n)*8+(k&7).
__device__ __forceinline__ int fslot(int k, int n) {
    return ((k >> 3) * 16 + n) * 8 + (k & 7);
}

// One block per matrix (12 blocks): shortens the serial pre-kernel bubble.
__global__ __launch_bounds__(BLK) void gate_kernel(
    const float* __restrict__ qw, __fp16* __restrict__ gout)
{
    __shared__ float G[NQ][8];
    const int t = threadIdx.x;
    const int mat = blockIdx.x;               // 0..11
    const int layer = mat / 3, ph = mat - 3 * layer;
    if (t < NQ) {
        const int p = layer * 3 * NQ + 3 * t;
        float t1 = qw[p], t2 = qw[p + 1], t3 = qw[p + 2];
        float a, b, c, d, gr, h;
        sincosf(0.5f * t1, &b, &a);   // RX
        sincosf(0.5f * t2, &d, &c);   // RY
        sincosf(0.5f * t3, &h, &gr);  // RZ
        float m00r =  c * a, m00i =  d * b;
        float m01r = -d * a, m01i = -c * b;
        float m10r =  d * a, m10i = -c * b;
        float m11r =  c * a, m11i = -d * b;
        float* g = G[t];
        g[0] = gr * m00r + h * m00i;  g[1] = gr * m00i - h * m00r;
        g[2] = gr * m01r + h * m01i;  g[3] = gr * m01i - h * m01r;
        g[4] = gr * m10r - h * m10i;  g[5] = gr * m10i + h * m10r;
        g[6] = gr * m11r - h * m11i;  g[7] = gr * m11i + h * m11r;
    }
    __syncthreads();
    const int n = t & 15, r = t >> 4;
    const int wbase = (ph == 0) ? 8 : (ph == 1) ? 4 : 0;
    float cr = 1.f, ci = 0.f;
    #pragma unroll
    for (int b = 0; b < 4; ++b) {         // bit (3-b) of row <-> wire wbase+b
        const float* g = G[wbase + b];
        const int rb = (r >> (3 - b)) & 1, nb = (n >> (3 - b)) & 1;
        const float er = g[(nb * 2 + rb) * 2], ei = g[(nb * 2 + rb) * 2 + 1];
        const float xr = cr * er - ci * ei, xi = cr * ei + ci * er;
        cr = xr; ci = xi;
    }
    __fp16* b1 = gout + (mat * 2 + 0) * 512;
    __fp16* b2 = gout + (mat * 2 + 1) * 512;
    b1[fslot(2 * r, n)]     = (__fp16)cr;
    b1[fslot(2 * r + 1, n)] = (__fp16)(-ci);
    b2[fslot(2 * r, n)]     = (__fp16)ci;
    b2[fslot(2 * r + 1, n)] = (__fp16)cr;
}

// A-fragment: lane (nn,g) k=8g..8g+7 -> amps r=4g..4g+3, (re,im) interleaved.
#define READ_FRAGS(AF, SRC)                                                 \
    _Pragma("unroll")                                                       \
    for (int q = 0; q < 4; ++q)                                             \
        AF[q] = __builtin_bit_cast(v8h, *(const uint4*)&sh[(SRC) +          \
                    lswz((((wv) << 6) | (q << 4) | nn) * 4 + g) * 8]);

// Shared B-fragments for both samples of the phase.
#define BLOAD(MAT)                                                          \
    const v8h b1 = gf[((MAT) * 2 + 0) * 64 + lane];                         \
    const v8h b2 = gf[((MAT) * 2 + 1) * 64 + lane];

#define MFMA_ONE(AF)                                                        \
    _Pragma("unroll")                                                       \
    for (int q = 0; q < 4; ++q) {                                           \
        d1[q] = __builtin_amdgcn_mfma_f32_16x16x32_f16(AF[q], b1, zf, 0, 0, 0); \
        d2[q] = __builtin_amdgcn_mfma_f32_16x16x32_f16(AF[q], b2, zf, 0, 0, 0); \
    }

// Keep the two samples' compute regions from being cross-pipelined
// (R2 lesson: interleaving doubles live accumulators -> VGPR cliff).
#define SCHB __builtin_amdgcn_sched_barrier(0);

// Element (q,rg): new row' = 4g+rg, col' = nn<<4|wv<<2|q -> one b128 per q.
#define WRITE_COLS(DST)                                                     \
    _Pragma("unroll")                                                       \
    for (int q = 0; q < 4; ++q) {                                           \
        const int CCn = (nn << 4) | (wv << 2) | q;                          \
        *(uint4*)&sh[(DST) + lswz(CCn * 4 + g) * 8] =                       \
            make_uint4(pk2(d1[q].x, d2[q].x), pk2(d1[q].y, d2[q].y),        \
                       pk2(d1[q].z, d2[q].z), pk2(d1[q].w, d2[q].w));       \
    }

// Phase-C out -> phase-A container with sigma folded in: b32 (re,im) scatter.
#define WRITE_SIGMA(DST)                                                    \
    _Pragma("unroll")                                                       \
    for (int q = 0; q < 4; ++q) {                                           \
        const int iq = ifix ^ sigma_inv_c(q << 4);                          \
        _Pragma("unroll")                                                   \
        for (int rg = 0; rg < 4; ++rg) {                                    \
            const int ii = iq ^ sigma_inv_c(rg);                            \
            *(unsigned*)&sh[(DST) + lswz(ii >> 2) * 8 + (ii & 3) * 2] =     \
                pk2(d1[q][rg], d2[q][rg]);                                  \
        }                                                                   \
    }

// Per-sample epilogue: WHT over (q,rg) -> signed vals -> 64-lane shuffle
// reduce -> lane0 writes red[OFF + wv*NQ..]. vals is block-scoped so the
// two samples' epilogues never hold vals live simultaneously (-12 VGPR
// vs R3's vals0/vals1 coexistence).
#define WHT_EPI(OFF)                                                        \
    { float pr[16];                                                         \
      _Pragma("unroll")                                                     \
      for (int q = 0; q < 4; ++q)                                           \
          _Pragma("unroll")                                                 \
          for (int rg = 0; rg < 4; ++rg)                                    \
              pr[q * 4 + rg] = d1[q][rg] * d1[q][rg] + d2[q][rg] * d2[q][rg]; \
      _Pragma("unroll")                                                     \
      for (int st = 1; st < 16; st <<= 1) {                                 \
          _Pragma("unroll")                                                 \
          for (int i = 0; i < 16; ++i) {                                    \
              if (!(i & st)) {                                              \
                  const float a = pr[i], b = pr[i ^ st];                    \
                  pr[i] = a + b; pr[i ^ st] = a - b;                        \
              }                                                             \
          }                                                                 \
      }                                                                     \
      float vals[NQ];                                                       \
      _Pragma("unroll")                                                     \
      for (int w = 0; w < NQ; ++w) {                                        \
          const int sb = 11 - w;                                            \
          const int f = (((sigma_inv_c(0x20) >> sb) & 1) << 3)              \
                      | (((sigma_inv_c(0x10) >> sb) & 1) << 2)              \
                      | (((sigma_inv_c(2)    >> sb) & 1) << 1)              \
                      |  ((sigma_inv_c(1)    >> sb) & 1);                   \
          const float v = pr[f];                                            \
          vals[w] = ((ifix >> sb) & 1) ? -v : v;                            \
      }                                                                     \
      _Pragma("unroll")                                                     \
      for (int m = 1; m <= 32; m <<= 1) {                                   \
          _Pragma("unroll")                                                 \
          for (int w = 0; w < NQ; ++w) vals[w] += __shfl_xor(vals[w], m);   \
      }                                                                     \
      if (lane == 0) {                                                      \
          _Pragma("unroll")                                                 \
          for (int w = 0; w < NQ; ++w) red[(OFF) + wv * NQ + w] = vals[w];  \
      } }

__global__ __launch_bounds__(BLK) void qsim_kernel(
    const float* __restrict__ x,      // (B, 12)
    const __fp16* __restrict__ gates, // 12 x (B1,B2) f16 fragment tables (d_ws)
    const float* __restrict__ dw,     // (12, 12)
    const float* __restrict__ db,     // (12,)
    float* __restrict__ out,          // (B, 12)
    int batch)
{
    // Two samples per block, each with a 16 KB in-place state buffer.
    // Gates are sample-independent, so B-fragments are shared per phase.
    __shared__ __align__(16) __fp16 sh[16384];
    float* xv    = (float*)sh;        // [0..23]
    float* enc_c = (float*)sh + 32;   // [32..55]
    float* enc_s = (float*)sh + 64;   // [64..87]
    float* red   = (float*)sh;

    const int tid  = threadIdx.x;
    const int lane = tid & 63;
    const int wv   = tid >> 6;
    const int s0   = 2 * blockIdx.x;
    int s1 = s0 + 1; if (s1 >= batch) s1 = batch - 1;   // odd-batch clamp
    const int nn = lane & 15, g = lane >> 4;
    const v8h* gf = (const v8h*)gates;
    const v4f zf = {0.f, 0.f, 0.f, 0.f};

    if (tid < 2 * NQ) {
        const int smp = tid / NQ, j = tid - smp * NQ;
        xv[tid] = x[(smp ? s1 : s0) * NQ + j];
    }
    __syncthreads();
    if (tid < 2 * NQ) {
        const int base = (tid / NQ) * NQ;
        float ss = 0.f;
        #pragma unroll
        for (int j = 0; j < NQ; ++j) ss += xv[base + j] * xv[base + j];
        float inv = rsqrtf(fmaxf(ss, 1e-12f));
        float mx = 0.f;
        #pragma unroll
        for (int j = 0; j < NQ; ++j) mx = fmaxf(mx, fabsf(xv[base + j] * inv));
        float ang = 3.14159265358979323846f * (xv[tid] * inv) / (mx + 1e-8f);
        float cc, sn;
        sincosf(0.5f * ang, &sn, &cc);
        enc_c[tid] = cc; enc_s[tid] = sn;
    }
    __syncthreads();

    // ---- product-state init as phase-A A-fragments (interleaved re/im) ----
    v8h af0[4], af1[4];
    #define PICK(SMP, W, B) ((B) ? enc_s[(SMP) * NQ + (W)] : enc_c[(SMP) * NQ + (W)])
    #define INIT_AF(AF, SMP)                                                \
    {   float R4[4];                                                        \
        _Pragma("unroll")                                                   \
        for (int t = 0; t < 4; ++t) {                                       \
            const int r = 4 * g + t;                                        \
            R4[t] = PICK(SMP, 8, (r >> 3) & 1) * PICK(SMP, 9, (r >> 2) & 1) \
                  * PICK(SMP, 10, (r >> 1) & 1) * PICK(SMP, 11, r & 1);     \
        }                                                                   \
        const float Pfix = PICK(SMP, 0, (wv >> 1) & 1) * PICK(SMP, 1, wv & 1) \
                         * PICK(SMP, 4, (nn >> 3) & 1) * PICK(SMP, 5, (nn >> 2) & 1) \
                         * PICK(SMP, 6, (nn >> 1) & 1) * PICK(SMP, 7, nn & 1); \
        _Pragma("unroll")                                                   \
        for (int q = 0; q < 4; ++q) {                                       \
            const float Pq = Pfix * PICK(SMP, 2, (q >> 1) & 1) * PICK(SMP, 3, q & 1); \
            _Pragma("unroll")                                               \
            for (int t = 0; t < 4; ++t) {                                   \
                AF[q][2 * t]     = (__fp16)(Pq * R4[t]);                    \
                AF[q][2 * t + 1] = (__fp16)0.f;                             \
            }                                                               \
        }                                                                   \
    }
    INIT_AF(af0, 0)
    INIT_AF(af1, 1)
    #undef PICK
    __syncthreads();   // enc reads done before state buffers are written

    const int ifix = sigma_inv_c((nn << 8) | (wv << 6) | (g << 2));

    v4f d1[4], d2[4];
    // ---- layers 0..NL-2: three phases each, sigma fold at layer end ----
    #pragma unroll 1
    for (int l = 0; l < NL - 1; ++l) {
        if (l > 0) {
            READ_FRAGS(af0, 0)
            READ_FRAGS(af1, S1OFF)
            __syncthreads();              // all reads landed before writes
        }
        { BLOAD(l * 3 + 0)                // wires 8..11
          MFMA_ONE(af0) WRITE_COLS(0)
          SCHB
          MFMA_ONE(af1) WRITE_COLS(S1OFF) }
        __syncthreads();

        READ_FRAGS(af0, 0)
        READ_FRAGS(af1, S1OFF)
        __syncthreads();
        { BLOAD(l * 3 + 1)                // wires 4..7
          MFMA_ONE(af0) WRITE_COLS(0)
          SCHB
          MFMA_ONE(af1) WRITE_COLS(S1OFF) }
        __syncthreads();

        READ_FRAGS(af0, 0)
        READ_FRAGS(af1, S1OFF)
        __syncthreads();
        { BLOAD(l * 3 + 2)                // wires 0..3 + CNOT ring fold
          MFMA_ONE(af0) WRITE_SIGMA(0)
          SCHB
          MFMA_ONE(af1) WRITE_SIGMA(S1OFF) }
        __syncthreads();
    }

    // ---- final layer (peeled): phases A, B, then C straight into epilogue ----
    READ_FRAGS(af0, 0)
    READ_FRAGS(af1, S1OFF)
    __syncthreads();
    { BLOAD((NL - 1) * 3 + 0)
      MFMA_ONE(af0) WRITE_COLS(0)
      SCHB
      MFMA_ONE(af1) WRITE_COLS(S1OFF) }
    __syncthreads();

    READ_FRAGS(af0, 0)
    READ_FRAGS(af1, S1OFF)
    __syncthreads();
    { BLOAD((NL - 1) * 3 + 1)
      MFMA_ONE(af0) WRITE_COLS(0)
      SCHB
      MFMA_ONE(af1) WRITE_COLS(S1OFF) }
    __syncthreads();

    READ_FRAGS(af0, 0)
    READ_FRAGS(af1, S1OFF)
    __syncthreads();   // all reads drained: sh is dead, red alias is safe
    { BLOAD((NL - 1) * 3 + 2)
      MFMA_ONE(af0)
      WHT_EPI(0)                          // s0: WHT+reduce+write, vals dies
      SCHB
      MFMA_ONE(af1)
      WHT_EPI(48) }                       // s1
    __syncthreads();

    if (tid < 2 * NQ) {
        const int smp = tid / NQ, w = tid - smp * NQ;
        const float* rs = red + smp * 48;
        red[96 + tid] = rs[w] + rs[NQ + w] + rs[2 * NQ + w] + rs[3 * NQ + w];
    }
    __syncthreads();
    if (tid < 2 * NQ) {
        const int smp = tid / NQ, o = tid - smp * NQ;
        const float* rv = red + 96 + smp * NQ;
        float v = db[o];
        #pragma unroll
        for (int w = 0; w < NQ; ++w) v += rv[w] * dw[w * NQ + o];
        out[(smp ? s1 : s0) * NQ + o] = tanhf(v);
    }
}

extern "C" void kernel_launch(void* const* d_in, const int* in_sizes, int n_in,
                              void* d_out, int out_size, void* d_ws, size_t ws_size,
                              hipStream_t stream) {
    const float* x  = (const float*)d_in[0];
    const float* qw = (const float*)d_in[1];
    const float* dw = (const float*)d_in[2];
    const float* db = (const float*)d_in[3];
    float* out = (float*)d_out;
    __fp16* gates = (__fp16*)d_ws;          // 12 x 2 x 512 f16 = 24576 B
    int batch = in_sizes[0] / NQ;
    int nblk = (batch + 1) / 2;
    gate_kernel<<<12, BLK, 0, stream>>>(qw, gates);
    qsim_kernel<<<nblk, BLK, 0, stream>>>(x, gates, dw, db, out, batch);
}